// Round 3
// baseline (133.299 us; speedup 1.0000x reference)
//
#include <hip/hip_runtime.h>
#include <math.h>

typedef unsigned long long u64;
typedef unsigned int u32;

#define NB      64
#define NPTS    12288
#define KTOP    10
#define NKP     9
#define T       1024
#define CAND_MAX 128
#define THETA   0.997f   // E[count] = 12288*0.003 ~= 37 per batch; exact slow path covers tails

// ---- one-pass config ----
#define CHUNKS   4
#define TPB_A    768     // 768 threads x 1 float4 = 3072 pts = 12288/4
#define CAP      64      // per-chunk survivor cap; Poisson(9.2) => P(>64) ~ 0
#define WS_STRIDE 320    // u64 per batch in data area: [0..3]=counts, [4..4+4*CAP)=cands
// ws layout: [ u32 ctr[NB] (256 B, memset to 0 each launch) | per-batch u64 data ]

// seg values are non-negative => IEEE bits monotone in value.
// pack = (bits(v)<<32) | ~idx  ==> u64 '>' == (v desc, idx asc) == jax.lax.top_k order.
__device__ __forceinline__ u64 pack(float v, int idx) {
    return ((u64)__float_as_uint(v) << 32) | (u32)(~idx);
}
__device__ __forceinline__ int unpack_idx(u64 p) { return (int)(~(u32)p); }

// fast (~1 ulp) hw ops — Kabsch only (continuous math, absmax margin ~3000x).
__device__ __forceinline__ float rcp_fast(float x)  { return __builtin_amdgcn_rcpf(x); }
__device__ __forceinline__ float rsq_fast(float x)  { return __builtin_amdgcn_rsqf(x); }
__device__ __forceinline__ float sqrt_fast(float x) { return __builtin_amdgcn_sqrtf(x); }

// =====================================================================
// One-pass kernel: 256 blocks (4 per batch). Each block filters its
// 3072-pt chunk into ws; the LAST block of each batch (device-scope
// atomic counter, threadfence release/acquire — standard last-block-done
// pattern, valid cross-XCD) inlines the solve for that batch. Removes
// the second launch AND the grid-wide join: batch b's solve overlaps
// other batches' filtering.
// =====================================================================
__global__ __launch_bounds__(TPB_A)
void pose_onepass(const float* __restrict__ pcld,   // [b, n, 3]
                  const float* __restrict__ kpts,   // [b, n, 8, 3]
                  const float* __restrict__ cpt,    // [b, n, 1, 3]
                  const float* __restrict__ seg,    // [b, n, 1]
                  const float* __restrict__ mesh,   // [b, 9, 3]
                  u32* __restrict__ ctr,            // [NB], zeroed by memset node
                  u64* __restrict__ wsd,            // per-batch data area
                  float* __restrict__ out)          // R[64,3,3] | t[64,3] | voted[64,9,3]
{
    const int blk   = blockIdx.x;
    const int b     = blk >> 2;
    const int chunk = blk & 3;
    const int t     = threadIdx.x;
    const int lane  = t & 63;

    __shared__ u64    lc[CAP];
    __shared__ int    lcnt;
    __shared__ int    last_s;
    __shared__ u64    cand[CHUNKS * CAP];
    __shared__ int    cnts_s[CHUNKS];
    __shared__ int    n_s, bad_s;
    __shared__ int    topidx[KTOP];
    __shared__ float4 cands4[NKP][KTOP];
    __shared__ float  voted[NKP][3];
    __shared__ float  meshS[NKP * 3];

    if (t == 0) lcnt = 0;
    __syncthreads();

    // ---- filter this block's 3072-pt chunk ----
    const float4* segc4 = (const float4*)(seg + (size_t)b * NPTS) + (size_t)chunk * TPB_A;
    float4 a = segc4[t];
    const int base_idx = chunk * (TPB_A * 4) + t * 4;   // point index within batch
    #pragma unroll
    for (int c = 0; c < 4; ++c) {
        float v = (c == 0) ? a.x : (c == 1) ? a.y : (c == 2) ? a.z : a.w;
        if (v >= THETA) {
            int slot = atomicAdd(&lcnt, 1);
            if (slot < CAP) lc[slot] = pack(v, base_idx + c);
        }
    }
    __syncthreads();

    u64* wb = wsd + (size_t)b * WS_STRIDE;
    if (t == 0) wb[chunk] = (u64)lcnt;                  // full count (solver detects overflow)
    int m = lcnt < CAP ? lcnt : CAP;
    if (t < m) wb[4 + chunk * CAP + t] = lc[t];
    __syncthreads();   // barrier drains vmem stores of all waves in this block

    // ---- last-block-done handoff (release: fence before atomic; acquire after) ----
    if (t == 0) {
        __threadfence();
        u32 old = atomicAdd(&ctr[b], 1u);
        if (old == 3u) __threadfence();
        last_s = (old == 3u) ? 1 : 0;
    }
    __syncthreads();
    if (!last_s) return;          // block-uniform exit; 3 of 4 blocks free their CU

    // =================== SOLVE (last block of this batch only) ===================
    // mesh prefetch + unconditional cand gather + counts read all issue in parallel
    float meshv = 0.0f;
    if (t < NKP * 3) meshv = mesh[(size_t)b * (NKP * 3) + t];
    if (t < CHUNKS * CAP) cand[t] = wb[4 + t];          // coalesced, count-independent
    if (t == 0) {
        int off = 0, badv = 0;
        #pragma unroll
        for (int c = 0; c < CHUNKS; ++c) {
            int cc = (int)wb[c];
            cnts_s[c] = cc < CAP ? cc : CAP;
            off += cc;
            if (cc > CAP) badv = 1;
        }
        n_s = off;
        bad_s = badv;
    }
    if (t < NKP * 3) meshS[t] = meshv;
    __syncthreads();

    const int n = n_s;
    const int bad = bad_s;

    // ---- top-10 by rank selection over the 4 chunk-segments (unique keys) ----
    if (!bad && n >= KTOP) {
        if (t < CHUNKS * CAP) {
            u64 my = cand[t];
            bool valid = (t & (CAP - 1)) < cnts_s[t >> 6];
            int r = 0;
            #pragma unroll
            for (int c2 = 0; c2 < CHUNKS; ++c2) {
                int cc = cnts_s[c2];
                for (int i2 = 0; i2 < cc; ++i2)
                    r += (cand[c2 * CAP + i2] > my) ? 1 : 0;
            }
            if (valid && r < KTOP) topidx[r] = unpack_idx(my);
        }
    } else if (t < 64) {
        // exact slow path (never taken for this data; correctness-only)
        const float* segb = seg + (size_t)b * NPTS;
        u64 loc[KTOP];
        #pragma unroll
        for (int j = 0; j < KTOP; ++j) loc[j] = 0;
        for (int i = lane; i < NPTS; i += 64) {
            u64 p = pack(segb[i], i);
            if (p > loc[KTOP - 1]) {
                loc[KTOP - 1] = p;
                #pragma unroll
                for (int j = KTOP - 1; j > 0; --j) {
                    if (loc[j] > loc[j - 1]) { u64 tmp = loc[j]; loc[j] = loc[j - 1]; loc[j - 1] = tmp; }
                }
            }
        }
        u64 cur = loc[0];
        #pragma unroll
        for (int k = 0; k < KTOP; ++k) {
            u64 w = cur;
            #pragma unroll
            for (int s = 1; s < 64; s <<= 1) {
                u64 o = __shfl_xor(w, s);
                w = o > w ? o : w;
            }
            if (lane == 0) topidx[k] = unpack_idx(w);
            if (cur == w) {
                #pragma unroll
                for (int i = 0; i + 1 < KTOP; ++i) loc[i] = loc[i + 1];
                loc[KTOP - 1] = 0;
                cur = loc[0];
            }
        }
    }
    __syncthreads();
    // topidx = batch-global top-10 indices in (v desc, idx asc) order == jax.lax.top_k.

    // ---- gather 9x10 candidate keypoints ----
    if (t < NKP * KTOP) {
        int j = t / KTOP;   // keypoint channel (0..7 = kpts offsets, 8 = cpt offset)
        int i = t % KTOP;   // candidate rank
        int p = topidx[i];
        size_t base = (size_t)b * NPTS + p;
        float px = pcld[base * 3 + 0], py = pcld[base * 3 + 1], pz = pcld[base * 3 + 2];
        float ox, oy, oz;
        if (j < 8) {
            size_t kb = (base * 8 + j) * 3;
            ox = kpts[kb + 0]; oy = kpts[kb + 1]; oz = kpts[kb + 2];
        } else {
            size_t cb = base * 3;
            ox = cpt[cb + 0]; oy = cpt[cb + 1]; oz = cpt[cb + 2];
        }
        cands4[j][i] = make_float4(px + ox, py + oy, pz + oz, 0.0f);
    }
    __syncthreads();

    // ---- sigma-clip clustering per keypoint (fp32, numpy order) ----
    if (t < NKP) {
        float4 c4[KTOP];
        #pragma unroll
        for (int i = 0; i < KTOP; ++i) c4[i] = cands4[t][i];

        float mean[3] = {0.f, 0.f, 0.f};
        #pragma unroll
        for (int i = 0; i < KTOP; ++i) {
            mean[0] += c4[i].x; mean[1] += c4[i].y; mean[2] += c4[i].z;
        }
        #pragma unroll
        for (int c = 0; c < 3; ++c) mean[c] *= (1.0f / KTOP);

        float var[3] = {0.f, 0.f, 0.f};
        #pragma unroll
        for (int i = 0; i < KTOP; ++i) {
            float d0 = c4[i].x - mean[0]; var[0] += d0 * d0;
            float d1 = c4[i].y - mean[1]; var[1] += d1 * d1;
            float d2 = c4[i].z - mean[2]; var[2] += d2 * d2;
        }
        float sd[3];
        #pragma unroll
        for (int c = 0; c < 3; ++c) sd[c] = sqrtf(var[c] * (1.0f / KTOP));  // precise: feeds <= test

        float wsum = 0.f, acc[3] = {0.f, 0.f, 0.f};
        #pragma unroll
        for (int i = 0; i < KTOP; ++i) {
            bool in = (fabsf(c4[i].x - mean[0]) <= sd[0]) &&
                      (fabsf(c4[i].y - mean[1]) <= sd[1]) &&
                      (fabsf(c4[i].z - mean[2]) <= sd[2]);
            if (in) {
                wsum += 1.f;
                acc[0] += c4[i].x; acc[1] += c4[i].y; acc[2] += c4[i].z;
            }
        }
        float inv = 1.f / (wsum + 1e-6f);   // precise: direct output
        #pragma unroll
        for (int c = 0; c < 3; ++c) {
            float v = acc[c] * inv;
            voted[t][c] = v;
            out[NB * 9 + NB * 3 + ((size_t)b * NKP + t) * 3 + c] = v;  // kpts_voted @768
        }
    }
    __syncthreads();

    // ---- weighted Kabsch (w = 1), 3x3 SVD via 5-sweep Jacobi on H^T H ----
    if (t == 0) {
        float A[NKP][3], Bv[NKP][3];
        float cA[3] = {0, 0, 0}, cB[3] = {0, 0, 0};
        for (int nn = 0; nn < NKP; ++nn) {
            for (int c = 0; c < 3; ++c) {
                A[nn][c]  = meshS[nn * 3 + c];
                Bv[nn][c] = voted[nn][c];
                cA[c] += A[nn][c];
                cB[c] += Bv[nn][c];
            }
        }
        for (int c = 0; c < 3; ++c) { cA[c] *= (1.0f / NKP); cB[c] *= (1.0f / NKP); }

        float H[3][3] = {{0,0,0},{0,0,0},{0,0,0}};
        for (int nn = 0; nn < NKP; ++nn)
            for (int i = 0; i < 3; ++i)
                for (int j = 0; j < 3; ++j)
                    H[i][j] += (A[nn][i] - cA[i]) * (Bv[nn][j] - cB[j]);

        float Km[3][3];
        for (int i = 0; i < 3; ++i)
            for (int j = 0; j < 3; ++j) {
                float s = 0;
                for (int l = 0; l < 3; ++l) s += H[l][i] * H[l][j];
                Km[i][j] = s;
            }

        float V[3][3] = {{1,0,0},{0,1,0},{0,0,1}};
        for (int sweep = 0; sweep < 5; ++sweep) {
            for (int p = 0; p < 2; ++p) {
                for (int q = p + 1; q < 3; ++q) {
                    float apq = Km[p][q];
                    float app = Km[p][p], aqq = Km[q][q];
                    if (fabsf(apq) <= 1e-12f * (fabsf(app) + fabsf(aqq)) || apq == 0.0f) continue;
                    float theta = (aqq - app) * rcp_fast(2.0f * apq);
                    float tj = ((theta >= 0.0f) ? 1.0f : -1.0f) *
                               rcp_fast(fabsf(theta) + sqrt_fast(theta * theta + 1.0f));
                    float cj = rsq_fast(tj * tj + 1.0f);
                    float sj = tj * cj;
                    for (int l = 0; l < 3; ++l) {
                        float klp = Km[l][p], klq = Km[l][q];
                        Km[l][p] = cj * klp - sj * klq;
                        Km[l][q] = sj * klp + cj * klq;
                    }
                    for (int l = 0; l < 3; ++l) {
                        float kpl = Km[p][l], kql = Km[q][l];
                        Km[p][l] = cj * kpl - sj * kql;
                        Km[q][l] = sj * kpl + cj * kql;
                    }
                    for (int l = 0; l < 3; ++l) {
                        float vlp = V[l][p], vlq = V[l][q];
                        V[l][p] = cj * vlp - sj * vlq;
                        V[l][q] = sj * vlp + cj * vlq;
                    }
                }
            }
        }

        float eig[3] = {Km[0][0], Km[1][1], Km[2][2]};
        int ord[3] = {0, 1, 2};
        if (eig[ord[0]] < eig[ord[1]]) { int tmp = ord[0]; ord[0] = ord[1]; ord[1] = tmp; }
        if (eig[ord[1]] < eig[ord[2]]) { int tmp = ord[1]; ord[1] = ord[2]; ord[2] = tmp; }
        if (eig[ord[0]] < eig[ord[1]]) { int tmp = ord[0]; ord[0] = ord[1]; ord[1] = tmp; }

        float detH =
            H[0][0] * (H[1][1] * H[2][2] - H[1][2] * H[2][1]) -
            H[0][1] * (H[1][0] * H[2][2] - H[1][2] * H[2][0]) +
            H[0][2] * (H[1][0] * H[2][1] - H[1][1] * H[2][0]);
        float dsign[3] = {1.0f, 1.0f, (detH < 0.0f) ? -1.0f : 1.0f};

        float R[3][3] = {{0,0,0},{0,0,0},{0,0,0}};
        for (int k = 0; k < 3; ++k) {
            int c = ord[k];
            float s = sqrt_fast(fmaxf(eig[c], 0.0f));
            float invs = rcp_fast(fmaxf(s, 1e-12f));
            float u[3];
            for (int l = 0; l < 3; ++l) {
                float a2 = 0;
                for (int mm = 0; mm < 3; ++mm) a2 += H[l][mm] * V[mm][c];
                u[l] = a2 * invs;
            }
            for (int r = 0; r < 3; ++r)
                for (int cc = 0; cc < 3; ++cc)
                    R[r][cc] += dsign[k] * V[r][c] * u[cc];
        }

        float tv[3];
        for (int c = 0; c < 3; ++c) {
            float a2 = 0;
            for (int mm = 0; mm < 3; ++mm) a2 += R[c][mm] * cA[mm];
            tv[c] = cB[c] - a2;
        }

        for (int r = 0; r < 3; ++r)
            for (int c = 0; c < 3; ++c)
                out[(size_t)b * 9 + r * 3 + c] = R[r][c];                // batch_R
        for (int c = 0; c < 3; ++c)
            out[NB * 9 + (size_t)b * 3 + c] = tv[c];                     // batch_t @576
    }
}

// =====================================================================
// Fallback: monolithic kernel (used only if ws is too small).
// =====================================================================
__global__ __launch_bounds__(T)
void pose_fused(const float* __restrict__ pcld,
                const float* __restrict__ kpts,
                const float* __restrict__ cpt,
                const float* __restrict__ seg,
                const float* __restrict__ mesh,
                float* __restrict__ out)
{
    const int b = blockIdx.x;
    const int t = threadIdx.x;
    const int lane = t & 63;
    const int wid = t >> 6;

    __shared__ u64    cand[CAND_MAX];
    __shared__ int    cnt;
    __shared__ int    topidx[KTOP];
    __shared__ float4 cands4[NKP][KTOP];
    __shared__ float  voted[NKP][3];
    __shared__ float  meshS[NKP * 3];

    if (t == 0) cnt = 0;
    float meshv = 0.0f;
    if (t < NKP * 3) meshv = mesh[(size_t)b * (NKP * 3) + t];
    __syncthreads();

    const float4* segb4 = (const float4*)(seg + (size_t)b * NPTS);
    #pragma unroll
    for (int j = 0; j < 3; ++j) {
        int f4 = t + j * T;
        float4 a = segb4[f4];
        #pragma unroll
        for (int c = 0; c < 4; ++c) {
            float v = (c == 0) ? a.x : (c == 1) ? a.y : (c == 2) ? a.z : a.w;
            if (v >= THETA) {
                int slot = atomicAdd(&cnt, 1);
                if (slot < CAND_MAX) cand[slot] = pack(v, 4 * f4 + c);
            }
        }
    }
    if (t < NKP * 3) meshS[t] = meshv;
    __syncthreads();

    if (wid == 0) {
        int n = cnt;
        if (n >= KTOP && n <= CAND_MAX) {
            u64 my0 = (lane < n)      ? cand[lane]      : 0;
            u64 my1 = (lane + 64 < n) ? cand[lane + 64] : 0;
            int r0 = 0, r1 = 0;
            for (int i = 0; i < n; ++i) {
                u64 ci = cand[i];
                r0 += (ci > my0) ? 1 : 0;
                r1 += (ci > my1) ? 1 : 0;
            }
            if (lane < n && r0 < KTOP)      topidx[r0] = unpack_idx(my0);
            if (lane + 64 < n && r1 < KTOP) topidx[r1] = unpack_idx(my1);
        } else {
            const float* segb = seg + (size_t)b * NPTS;
            u64 loc[KTOP];
            #pragma unroll
            for (int j = 0; j < KTOP; ++j) loc[j] = 0;
            for (int i = lane; i < NPTS; i += 64) {
                u64 p = pack(segb[i], i);
                if (p > loc[KTOP - 1]) {
                    loc[KTOP - 1] = p;
                    #pragma unroll
                    for (int j = KTOP - 1; j > 0; --j) {
                        if (loc[j] > loc[j - 1]) { u64 tmp = loc[j]; loc[j] = loc[j - 1]; loc[j - 1] = tmp; }
                    }
                }
            }
            u64 cur = loc[0];
            #pragma unroll
            for (int k = 0; k < KTOP; ++k) {
                u64 w = cur;
                #pragma unroll
                for (int s = 1; s < 64; s <<= 1) {
                    u64 o = __shfl_xor(w, s);
                    w = o > w ? o : w;
                }
                if (lane == 0) topidx[k] = unpack_idx(w);
                if (cur == w) {
                    #pragma unroll
                    for (int i = 0; i + 1 < KTOP; ++i) loc[i] = loc[i + 1];
                    loc[KTOP - 1] = 0;
                    cur = loc[0];
                }
            }
        }
    }
    __syncthreads();

    if (t < NKP * KTOP) {
        int j = t / KTOP;
        int i = t % KTOP;
        int p = topidx[i];
        size_t base = (size_t)b * NPTS + p;
        float px = pcld[base * 3 + 0], py = pcld[base * 3 + 1], pz = pcld[base * 3 + 2];
        float ox, oy, oz;
        if (j < 8) {
            size_t kb = (base * 8 + j) * 3;
            ox = kpts[kb + 0]; oy = kpts[kb + 1]; oz = kpts[kb + 2];
        } else {
            size_t cb = base * 3;
            ox = cpt[cb + 0]; oy = cpt[cb + 1]; oz = cpt[cb + 2];
        }
        cands4[j][i] = make_float4(px + ox, py + oy, pz + oz, 0.0f);
    }
    __syncthreads();

    if (t < NKP) {
        float4 c4[KTOP];
        #pragma unroll
        for (int i = 0; i < KTOP; ++i) c4[i] = cands4[t][i];
        float mean[3] = {0.f, 0.f, 0.f};
        #pragma unroll
        for (int i = 0; i < KTOP; ++i) { mean[0] += c4[i].x; mean[1] += c4[i].y; mean[2] += c4[i].z; }
        #pragma unroll
        for (int c = 0; c < 3; ++c) mean[c] *= (1.0f / KTOP);
        float var[3] = {0.f, 0.f, 0.f};
        #pragma unroll
        for (int i = 0; i < KTOP; ++i) {
            float d0 = c4[i].x - mean[0]; var[0] += d0 * d0;
            float d1 = c4[i].y - mean[1]; var[1] += d1 * d1;
            float d2 = c4[i].z - mean[2]; var[2] += d2 * d2;
        }
        float sd[3];
        #pragma unroll
        for (int c = 0; c < 3; ++c) sd[c] = sqrtf(var[c] * (1.0f / KTOP));
        float wsum = 0.f, acc[3] = {0.f, 0.f, 0.f};
        #pragma unroll
        for (int i = 0; i < KTOP; ++i) {
            bool in = (fabsf(c4[i].x - mean[0]) <= sd[0]) &&
                      (fabsf(c4[i].y - mean[1]) <= sd[1]) &&
                      (fabsf(c4[i].z - mean[2]) <= sd[2]);
            if (in) { wsum += 1.f; acc[0] += c4[i].x; acc[1] += c4[i].y; acc[2] += c4[i].z; }
        }
        float inv = 1.f / (wsum + 1e-6f);
        #pragma unroll
        for (int c = 0; c < 3; ++c) {
            float v = acc[c] * inv;
            voted[t][c] = v;
            out[NB * 9 + NB * 3 + ((size_t)b * NKP + t) * 3 + c] = v;
        }
    }
    __syncthreads();

    if (t == 0) {
        float A[NKP][3], Bv[NKP][3];
        float cA[3] = {0, 0, 0}, cB[3] = {0, 0, 0};
        for (int nn = 0; nn < NKP; ++nn) {
            for (int c = 0; c < 3; ++c) {
                A[nn][c]  = meshS[nn * 3 + c];
                Bv[nn][c] = voted[nn][c];
                cA[c] += A[nn][c];
                cB[c] += Bv[nn][c];
            }
        }
        for (int c = 0; c < 3; ++c) { cA[c] *= (1.0f / NKP); cB[c] *= (1.0f / NKP); }
        float H[3][3] = {{0,0,0},{0,0,0},{0,0,0}};
        for (int nn = 0; nn < NKP; ++nn)
            for (int i = 0; i < 3; ++i)
                for (int j = 0; j < 3; ++j)
                    H[i][j] += (A[nn][i] - cA[i]) * (Bv[nn][j] - cB[j]);
        float Km[3][3];
        for (int i = 0; i < 3; ++i)
            for (int j = 0; j < 3; ++j) {
                float s = 0;
                for (int l = 0; l < 3; ++l) s += H[l][i] * H[l][j];
                Km[i][j] = s;
            }
        float V[3][3] = {{1,0,0},{0,1,0},{0,0,1}};
        for (int sweep = 0; sweep < 5; ++sweep) {
            for (int p = 0; p < 2; ++p) {
                for (int q = p + 1; q < 3; ++q) {
                    float apq = Km[p][q];
                    float app = Km[p][p], aqq = Km[q][q];
                    if (fabsf(apq) <= 1e-12f * (fabsf(app) + fabsf(aqq)) || apq == 0.0f) continue;
                    float theta = (aqq - app) * rcp_fast(2.0f * apq);
                    float tj = ((theta >= 0.0f) ? 1.0f : -1.0f) *
                               rcp_fast(fabsf(theta) + sqrt_fast(theta * theta + 1.0f));
                    float cj = rsq_fast(tj * tj + 1.0f);
                    float sj = tj * cj;
                    for (int l = 0; l < 3; ++l) {
                        float klp = Km[l][p], klq = Km[l][q];
                        Km[l][p] = cj * klp - sj * klq;
                        Km[l][q] = sj * klp + cj * klq;
                    }
                    for (int l = 0; l < 3; ++l) {
                        float kpl = Km[p][l], kql = Km[q][l];
                        Km[p][l] = cj * kpl - sj * kql;
                        Km[q][l] = sj * kpl + cj * kql;
                    }
                    for (int l = 0; l < 3; ++l) {
                        float vlp = V[l][p], vlq = V[l][q];
                        V[l][p] = cj * vlp - sj * vlq;
                        V[l][q] = sj * vlp + cj * vlq;
                    }
                }
            }
        }
        float eig[3] = {Km[0][0], Km[1][1], Km[2][2]};
        int ord[3] = {0, 1, 2};
        if (eig[ord[0]] < eig[ord[1]]) { int tmp = ord[0]; ord[0] = ord[1]; ord[1] = tmp; }
        if (eig[ord[1]] < eig[ord[2]]) { int tmp = ord[1]; ord[1] = ord[2]; ord[2] = tmp; }
        if (eig[ord[0]] < eig[ord[1]]) { int tmp = ord[0]; ord[0] = ord[1]; ord[1] = tmp; }
        float detH =
            H[0][0] * (H[1][1] * H[2][2] - H[1][2] * H[2][1]) -
            H[0][1] * (H[1][0] * H[2][2] - H[1][2] * H[2][0]) +
            H[0][2] * (H[1][0] * H[2][1] - H[1][1] * H[2][0]);
        float dsign[3] = {1.0f, 1.0f, (detH < 0.0f) ? -1.0f : 1.0f};
        float R[3][3] = {{0,0,0},{0,0,0},{0,0,0}};
        for (int k = 0; k < 3; ++k) {
            int c = ord[k];
            float s = sqrt_fast(fmaxf(eig[c], 0.0f));
            float invs = rcp_fast(fmaxf(s, 1e-12f));
            float u[3];
            for (int l = 0; l < 3; ++l) {
                float a2 = 0;
                for (int mm = 0; mm < 3; ++mm) a2 += H[l][mm] * V[mm][c];
                u[l] = a2 * invs;
            }
            for (int r = 0; r < 3; ++r)
                for (int cc = 0; cc < 3; ++cc)
                    R[r][cc] += dsign[k] * V[r][c] * u[cc];
        }
        float tv[3];
        for (int c = 0; c < 3; ++c) {
            float a2 = 0;
            for (int mm = 0; mm < 3; ++mm) a2 += R[c][mm] * cA[mm];
            tv[c] = cB[c] - a2;
        }
        for (int r = 0; r < 3; ++r)
            for (int c = 0; c < 3; ++c)
                out[(size_t)b * 9 + r * 3 + c] = R[r][c];
        for (int c = 0; c < 3; ++c)
            out[NB * 9 + (size_t)b * 3 + c] = tv[c];
    }
}

extern "C" void kernel_launch(void* const* d_in, const int* in_sizes, int n_in,
                              void* d_out, int out_size, void* d_ws, size_t ws_size,
                              hipStream_t stream) {
    const float* pcld = (const float*)d_in[0];   // [64,12288,3]
    const float* kpts = (const float*)d_in[1];   // [64,12288,8,3]
    const float* cpt  = (const float*)d_in[2];   // [64,12288,1,3]
    const float* seg  = (const float*)d_in[3];   // [64,12288,1]
    const float* mesh = (const float*)d_in[4];   // [64,9,3]
    float* out = (float*)d_out;                  // 576 (R) + 192 (t) + 1728 (voted)

    const size_t need = 256 + (size_t)NB * WS_STRIDE * sizeof(u64);   // 256 B ctr + 160 KB data
    if (d_ws != nullptr && ws_size >= need) {
        u32* ctr = (u32*)d_ws;
        u64* wsd = (u64*)((char*)d_ws + 256);
        // zero the 64 per-batch arrival counters (graph-capturable memset node)
        hipMemsetAsync(d_ws, 0, NB * sizeof(u32), stream);
        pose_onepass<<<NB * CHUNKS, TPB_A, 0, stream>>>(pcld, kpts, cpt, seg, mesh, ctr, wsd, out);
    } else {
        pose_fused<<<NB, T, 0, stream>>>(pcld, kpts, cpt, seg, mesh, out);
    }
}

// Round 4
// 119.013 us; speedup vs baseline: 1.1200x; 1.1200x over previous
//
#include <hip/hip_runtime.h>
#include <math.h>

typedef unsigned long long u64;
typedef unsigned int u32;

#define NB      64
#define NPTS    12288
#define KTOP    10
#define NKP     9
#define T       1024
#define CAND_MAX 128
#define THETA   0.997f   // E[count] = 12288*0.003 ~= 37 per batch; exact slow path covers tails

// ---- split-kernel config (R2 structure: empirically best, 120.2 us) ----
#define CHUNKS   4
#define TPB_A    768     // 768 threads x 1 float4 = 3072 pts = 12288/4
#define CAP      64      // per-chunk survivor cap; Poisson(9.2) => P(>64) ~ 0
#define TPB_B    256     // one thread per candidate slot (CHUNKS*CAP = 256)
#define WS_STRIDE 320    // u64 per batch: [0..3]=chunk counts, [4..4+4*CAP)=cands

// seg values are non-negative => IEEE bits monotone in value.
// pack = (bits(v)<<32) | ~idx  ==> u64 '>' == (v desc, idx asc) == jax.lax.top_k order.
__device__ __forceinline__ u64 pack(float v, int idx) {
    return ((u64)__float_as_uint(v) << 32) | (u32)(~idx);
}
__device__ __forceinline__ int unpack_idx(u64 p) { return (int)(~(u32)p); }

// fast (~1 ulp) hw ops — Kabsch only (continuous math, absmax margin ~3000x).
__device__ __forceinline__ float rcp_fast(float x)  { return __builtin_amdgcn_rcpf(x); }
__device__ __forceinline__ float rsq_fast(float x)  { return __builtin_amdgcn_rsqf(x); }
__device__ __forceinline__ float sqrt_fast(float x) { return __builtin_amdgcn_sqrtf(x); }

// =====================================================================
// Kernel A (verbatim R2): threshold filter. 256 blocks (4 per batch),
// 1 float4/thread. Survivors -> private ws region (no global atomics,
// no ws pre-zero: counts unconditionally written every run).
// =====================================================================
__global__ __launch_bounds__(TPB_A)
void pose_filter(const float* __restrict__ seg, u64* __restrict__ ws)
{
    const int blk   = blockIdx.x;
    const int b     = blk >> 2;
    const int chunk = blk & 3;
    const int t     = threadIdx.x;

    __shared__ u64 lc[CAP];
    __shared__ int lcnt;
    if (t == 0) lcnt = 0;
    __syncthreads();

    const float4* segc4 = (const float4*)(seg + (size_t)b * NPTS) + (size_t)chunk * TPB_A;
    float4 a = segc4[t];
    const int base_idx = chunk * (TPB_A * 4) + t * 4;   // point index within batch
    #pragma unroll
    for (int c = 0; c < 4; ++c) {
        float v = (c == 0) ? a.x : (c == 1) ? a.y : (c == 2) ? a.z : a.w;
        if (v >= THETA) {
            int slot = atomicAdd(&lcnt, 1);
            if (slot < CAP) lc[slot] = pack(v, base_idx + c);
        }
    }
    __syncthreads();

    u64* wb = ws + (size_t)b * WS_STRIDE;
    if (t == 0) wb[chunk] = (u64)lcnt;                  // full count (B detects overflow)
    int m = lcnt < CAP ? lcnt : CAP;
    if (t < m) wb[4 + chunk * CAP + t] = lc[t];
}

// =====================================================================
// Kernel B: select top-10 + gather + sigma-clip + Kabsch. 64 blocks x 256.
// Changes vs R2 (each validated in R3's solve path):
//   - candidate gather is UNCONDITIONAL (no count->gather dependency)
//   - per-chunk validity replaces the serial t==0 prefix-scan
//   - one thread per slot: rank selection has no 2-element inner loop
// =====================================================================
__global__ __launch_bounds__(TPB_B)
void pose_solve(const float* __restrict__ pcld,   // [b, n, 3]
                const float* __restrict__ kpts,   // [b, n, 8, 3]
                const float* __restrict__ cpt,    // [b, n, 1, 3]
                const float* __restrict__ seg,    // [b, n, 1]
                const float* __restrict__ mesh,   // [b, 9, 3]
                const u64*   __restrict__ ws,
                float* __restrict__ out)          // R[64,3,3] | t[64,3] | voted[64,9,3]
{
    const int b = blockIdx.x;
    const int t = threadIdx.x;
    const int lane = t & 63;

    __shared__ u64    cand[CHUNKS * CAP];
    __shared__ int    cntf_s[CHUNKS];      // full per-chunk counts (overflow-detecting)
    __shared__ int    topidx[KTOP];
    __shared__ float4 cands4[NKP][KTOP];
    __shared__ float  voted[NKP][3];
    __shared__ float  meshS[NKP * 3];

    const u64* wb = ws + (size_t)b * WS_STRIDE;

    // all loads issue in parallel: mesh prefetch, unconditional slot gather, counts
    float meshv = 0.0f;
    if (t < NKP * 3) meshv = mesh[(size_t)b * (NKP * 3) + t];
    cand[t] = wb[4 + t];                   // coalesced 256x8B, count-independent
    if (t < CHUNKS) cntf_s[t] = (int)wb[t];
    if (t < NKP * 3) meshS[t] = meshv;
    __syncthreads();

    // block-uniform n / bad from shared (no serial prefix)
    int cnts[CHUNKS];
    int n = 0, bad = 0;
    #pragma unroll
    for (int c = 0; c < CHUNKS; ++c) {
        int cc = cntf_s[c];
        n += cc;
        if (cc > CAP) bad = 1;
        cnts[c] = cc < CAP ? cc : CAP;
    }

    // ---- top-10 by rank selection, one thread per slot (unique keys) ----
    if (!bad && n >= KTOP) {
        u64 my = cand[t];
        bool valid = (t & (CAP - 1)) < cnts[t >> 6];
        int r = 0;
        #pragma unroll
        for (int c2 = 0; c2 < CHUNKS; ++c2) {
            int cc = cnts[c2];
            for (int i2 = 0; i2 < cc; ++i2)
                r += (cand[c2 * CAP + i2] > my) ? 1 : 0;
        }
        if (valid && r < KTOP) topidx[r] = unpack_idx(my);
    } else if (t < 64) {
        // exact slow path (never taken for this data; correctness-only)
        const float* segb = seg + (size_t)b * NPTS;
        u64 loc[KTOP];
        #pragma unroll
        for (int j = 0; j < KTOP; ++j) loc[j] = 0;
        for (int i = lane; i < NPTS; i += 64) {
            u64 p = pack(segb[i], i);
            if (p > loc[KTOP - 1]) {
                loc[KTOP - 1] = p;
                #pragma unroll
                for (int j = KTOP - 1; j > 0; --j) {
                    if (loc[j] > loc[j - 1]) { u64 tmp = loc[j]; loc[j] = loc[j - 1]; loc[j - 1] = tmp; }
                }
            }
        }
        u64 cur = loc[0];
        #pragma unroll
        for (int k = 0; k < KTOP; ++k) {
            u64 w = cur;
            #pragma unroll
            for (int s = 1; s < 64; s <<= 1) {
                u64 o = __shfl_xor(w, s);
                w = o > w ? o : w;
            }
            if (lane == 0) topidx[k] = unpack_idx(w);
            if (cur == w) {
                #pragma unroll
                for (int i = 0; i + 1 < KTOP; ++i) loc[i] = loc[i + 1];
                loc[KTOP - 1] = 0;
                cur = loc[0];
            }
        }
    }
    __syncthreads();
    // topidx = batch-global top-10 indices in (v desc, idx asc) order == jax.lax.top_k.

    // ---- gather 9x10 candidate keypoints ----
    if (t < NKP * KTOP) {
        int j = t / KTOP;   // keypoint channel (0..7 = kpts offsets, 8 = cpt offset)
        int i = t % KTOP;   // candidate rank
        int p = topidx[i];
        size_t base = (size_t)b * NPTS + p;
        float px = pcld[base * 3 + 0], py = pcld[base * 3 + 1], pz = pcld[base * 3 + 2];
        float ox, oy, oz;
        if (j < 8) {
            size_t kb = (base * 8 + j) * 3;
            ox = kpts[kb + 0]; oy = kpts[kb + 1]; oz = kpts[kb + 2];
        } else {
            size_t cb = base * 3;
            ox = cpt[cb + 0]; oy = cpt[cb + 1]; oz = cpt[cb + 2];
        }
        cands4[j][i] = make_float4(px + ox, py + oy, pz + oz, 0.0f);
    }
    __syncthreads();

    // ---- sigma-clip clustering per keypoint (fp32, numpy order) ----
    if (t < NKP) {
        float4 c4[KTOP];
        #pragma unroll
        for (int i = 0; i < KTOP; ++i) c4[i] = cands4[t][i];

        float mean[3] = {0.f, 0.f, 0.f};
        #pragma unroll
        for (int i = 0; i < KTOP; ++i) {
            mean[0] += c4[i].x; mean[1] += c4[i].y; mean[2] += c4[i].z;
        }
        #pragma unroll
        for (int c = 0; c < 3; ++c) mean[c] *= (1.0f / KTOP);

        float var[3] = {0.f, 0.f, 0.f};
        #pragma unroll
        for (int i = 0; i < KTOP; ++i) {
            float d0 = c4[i].x - mean[0]; var[0] += d0 * d0;
            float d1 = c4[i].y - mean[1]; var[1] += d1 * d1;
            float d2 = c4[i].z - mean[2]; var[2] += d2 * d2;
        }
        float sd[3];
        #pragma unroll
        for (int c = 0; c < 3; ++c) sd[c] = sqrtf(var[c] * (1.0f / KTOP));  // precise: feeds <= test

        float wsum = 0.f, acc[3] = {0.f, 0.f, 0.f};
        #pragma unroll
        for (int i = 0; i < KTOP; ++i) {
            bool in = (fabsf(c4[i].x - mean[0]) <= sd[0]) &&
                      (fabsf(c4[i].y - mean[1]) <= sd[1]) &&
                      (fabsf(c4[i].z - mean[2]) <= sd[2]);
            if (in) {
                wsum += 1.f;
                acc[0] += c4[i].x; acc[1] += c4[i].y; acc[2] += c4[i].z;
            }
        }
        float inv = 1.f / (wsum + 1e-6f);   // precise: direct output
        #pragma unroll
        for (int c = 0; c < 3; ++c) {
            float v = acc[c] * inv;
            voted[t][c] = v;
            out[NB * 9 + NB * 3 + ((size_t)b * NKP + t) * 3 + c] = v;  // kpts_voted @768
        }
    }
    __syncthreads();

    // ---- weighted Kabsch (w = 1), 3x3 SVD via 5-sweep Jacobi on H^T H ----
    if (t == 0) {
        float A[NKP][3], Bv[NKP][3];
        float cA[3] = {0, 0, 0}, cB[3] = {0, 0, 0};
        for (int nn = 0; nn < NKP; ++nn) {
            for (int c = 0; c < 3; ++c) {
                A[nn][c]  = meshS[nn * 3 + c];
                Bv[nn][c] = voted[nn][c];
                cA[c] += A[nn][c];
                cB[c] += Bv[nn][c];
            }
        }
        for (int c = 0; c < 3; ++c) { cA[c] *= (1.0f / NKP); cB[c] *= (1.0f / NKP); }

        float H[3][3] = {{0,0,0},{0,0,0},{0,0,0}};
        for (int nn = 0; nn < NKP; ++nn)
            for (int i = 0; i < 3; ++i)
                for (int j = 0; j < 3; ++j)
                    H[i][j] += (A[nn][i] - cA[i]) * (Bv[nn][j] - cB[j]);

        float Km[3][3];
        for (int i = 0; i < 3; ++i)
            for (int j = 0; j < 3; ++j) {
                float s = 0;
                for (int l = 0; l < 3; ++l) s += H[l][i] * H[l][j];
                Km[i][j] = s;
            }

        float V[3][3] = {{1,0,0},{0,1,0},{0,0,1}};
        for (int sweep = 0; sweep < 5; ++sweep) {
            for (int p = 0; p < 2; ++p) {
                for (int q = p + 1; q < 3; ++q) {
                    float apq = Km[p][q];
                    float app = Km[p][p], aqq = Km[q][q];
                    if (fabsf(apq) <= 1e-12f * (fabsf(app) + fabsf(aqq)) || apq == 0.0f) continue;
                    float theta = (aqq - app) * rcp_fast(2.0f * apq);
                    float tj = ((theta >= 0.0f) ? 1.0f : -1.0f) *
                               rcp_fast(fabsf(theta) + sqrt_fast(theta * theta + 1.0f));
                    float cj = rsq_fast(tj * tj + 1.0f);
                    float sj = tj * cj;
                    for (int l = 0; l < 3; ++l) {
                        float klp = Km[l][p], klq = Km[l][q];
                        Km[l][p] = cj * klp - sj * klq;
                        Km[l][q] = sj * klp + cj * klq;
                    }
                    for (int l = 0; l < 3; ++l) {
                        float kpl = Km[p][l], kql = Km[q][l];
                        Km[p][l] = cj * kpl - sj * kql;
                        Km[q][l] = sj * kpl + cj * kql;
                    }
                    for (int l = 0; l < 3; ++l) {
                        float vlp = V[l][p], vlq = V[l][q];
                        V[l][p] = cj * vlp - sj * vlq;
                        V[l][q] = sj * vlp + cj * vlq;
                    }
                }
            }
        }

        float eig[3] = {Km[0][0], Km[1][1], Km[2][2]};
        int ord[3] = {0, 1, 2};
        if (eig[ord[0]] < eig[ord[1]]) { int tmp = ord[0]; ord[0] = ord[1]; ord[1] = tmp; }
        if (eig[ord[1]] < eig[ord[2]]) { int tmp = ord[1]; ord[1] = ord[2]; ord[2] = tmp; }
        if (eig[ord[0]] < eig[ord[1]]) { int tmp = ord[0]; ord[0] = ord[1]; ord[1] = tmp; }

        float detH =
            H[0][0] * (H[1][1] * H[2][2] - H[1][2] * H[2][1]) -
            H[0][1] * (H[1][0] * H[2][2] - H[1][2] * H[2][0]) +
            H[0][2] * (H[1][0] * H[2][1] - H[1][1] * H[2][0]);
        float dsign[3] = {1.0f, 1.0f, (detH < 0.0f) ? -1.0f : 1.0f};

        float R[3][3] = {{0,0,0},{0,0,0},{0,0,0}};
        for (int k = 0; k < 3; ++k) {
            int c = ord[k];
            float s = sqrt_fast(fmaxf(eig[c], 0.0f));
            float invs = rcp_fast(fmaxf(s, 1e-12f));
            float u[3];
            for (int l = 0; l < 3; ++l) {
                float a2 = 0;
                for (int mm = 0; mm < 3; ++mm) a2 += H[l][mm] * V[mm][c];
                u[l] = a2 * invs;
            }
            for (int r = 0; r < 3; ++r)
                for (int cc = 0; cc < 3; ++cc)
                    R[r][cc] += dsign[k] * V[r][c] * u[cc];
        }

        float tv[3];
        for (int c = 0; c < 3; ++c) {
            float a2 = 0;
            for (int mm = 0; mm < 3; ++mm) a2 += R[c][mm] * cA[mm];
            tv[c] = cB[c] - a2;
        }

        for (int r = 0; r < 3; ++r)
            for (int c = 0; c < 3; ++c)
                out[(size_t)b * 9 + r * 3 + c] = R[r][c];                // batch_R
        for (int c = 0; c < 3; ++c)
            out[NB * 9 + (size_t)b * 3 + c] = tv[c];                     // batch_t @576
    }
}

// =====================================================================
// Fallback: monolithic kernel (used only if ws is too small).
// =====================================================================
__global__ __launch_bounds__(T)
void pose_fused(const float* __restrict__ pcld,
                const float* __restrict__ kpts,
                const float* __restrict__ cpt,
                const float* __restrict__ seg,
                const float* __restrict__ mesh,
                float* __restrict__ out)
{
    const int b = blockIdx.x;
    const int t = threadIdx.x;
    const int lane = t & 63;
    const int wid = t >> 6;

    __shared__ u64    cand[CAND_MAX];
    __shared__ int    cnt;
    __shared__ int    topidx[KTOP];
    __shared__ float4 cands4[NKP][KTOP];
    __shared__ float  voted[NKP][3];
    __shared__ float  meshS[NKP * 3];

    if (t == 0) cnt = 0;
    float meshv = 0.0f;
    if (t < NKP * 3) meshv = mesh[(size_t)b * (NKP * 3) + t];
    __syncthreads();

    const float4* segb4 = (const float4*)(seg + (size_t)b * NPTS);
    #pragma unroll
    for (int j = 0; j < 3; ++j) {
        int f4 = t + j * T;
        float4 a = segb4[f4];
        #pragma unroll
        for (int c = 0; c < 4; ++c) {
            float v = (c == 0) ? a.x : (c == 1) ? a.y : (c == 2) ? a.z : a.w;
            if (v >= THETA) {
                int slot = atomicAdd(&cnt, 1);
                if (slot < CAND_MAX) cand[slot] = pack(v, 4 * f4 + c);
            }
        }
    }
    if (t < NKP * 3) meshS[t] = meshv;
    __syncthreads();

    if (wid == 0) {
        int n = cnt;
        if (n >= KTOP && n <= CAND_MAX) {
            u64 my0 = (lane < n)      ? cand[lane]      : 0;
            u64 my1 = (lane + 64 < n) ? cand[lane + 64] : 0;
            int r0 = 0, r1 = 0;
            for (int i = 0; i < n; ++i) {
                u64 ci = cand[i];
                r0 += (ci > my0) ? 1 : 0;
                r1 += (ci > my1) ? 1 : 0;
            }
            if (lane < n && r0 < KTOP)      topidx[r0] = unpack_idx(my0);
            if (lane + 64 < n && r1 < KTOP) topidx[r1] = unpack_idx(my1);
        } else {
            const float* segb = seg + (size_t)b * NPTS;
            u64 loc[KTOP];
            #pragma unroll
            for (int j = 0; j < KTOP; ++j) loc[j] = 0;
            for (int i = lane; i < NPTS; i += 64) {
                u64 p = pack(segb[i], i);
                if (p > loc[KTOP - 1]) {
                    loc[KTOP - 1] = p;
                    #pragma unroll
                    for (int j = KTOP - 1; j > 0; --j) {
                        if (loc[j] > loc[j - 1]) { u64 tmp = loc[j]; loc[j] = loc[j - 1]; loc[j - 1] = tmp; }
                    }
                }
            }
            u64 cur = loc[0];
            #pragma unroll
            for (int k = 0; k < KTOP; ++k) {
                u64 w = cur;
                #pragma unroll
                for (int s = 1; s < 64; s <<= 1) {
                    u64 o = __shfl_xor(w, s);
                    w = o > w ? o : w;
                }
                if (lane == 0) topidx[k] = unpack_idx(w);
                if (cur == w) {
                    #pragma unroll
                    for (int i = 0; i + 1 < KTOP; ++i) loc[i] = loc[i + 1];
                    loc[KTOP - 1] = 0;
                    cur = loc[0];
                }
            }
        }
    }
    __syncthreads();

    if (t < NKP * KTOP) {
        int j = t / KTOP;
        int i = t % KTOP;
        int p = topidx[i];
        size_t base = (size_t)b * NPTS + p;
        float px = pcld[base * 3 + 0], py = pcld[base * 3 + 1], pz = pcld[base * 3 + 2];
        float ox, oy, oz;
        if (j < 8) {
            size_t kb = (base * 8 + j) * 3;
            ox = kpts[kb + 0]; oy = kpts[kb + 1]; oz = kpts[kb + 2];
        } else {
            size_t cb = base * 3;
            ox = cpt[cb + 0]; oy = cpt[cb + 1]; oz = cpt[cb + 2];
        }
        cands4[j][i] = make_float4(px + ox, py + oy, pz + oz, 0.0f);
    }
    __syncthreads();

    if (t < NKP) {
        float4 c4[KTOP];
        #pragma unroll
        for (int i = 0; i < KTOP; ++i) c4[i] = cands4[t][i];
        float mean[3] = {0.f, 0.f, 0.f};
        #pragma unroll
        for (int i = 0; i < KTOP; ++i) { mean[0] += c4[i].x; mean[1] += c4[i].y; mean[2] += c4[i].z; }
        #pragma unroll
        for (int c = 0; c < 3; ++c) mean[c] *= (1.0f / KTOP);
        float var[3] = {0.f, 0.f, 0.f};
        #pragma unroll
        for (int i = 0; i < KTOP; ++i) {
            float d0 = c4[i].x - mean[0]; var[0] += d0 * d0;
            float d1 = c4[i].y - mean[1]; var[1] += d1 * d1;
            float d2 = c4[i].z - mean[2]; var[2] += d2 * d2;
        }
        float sd[3];
        #pragma unroll
        for (int c = 0; c < 3; ++c) sd[c] = sqrtf(var[c] * (1.0f / KTOP));
        float wsum = 0.f, acc[3] = {0.f, 0.f, 0.f};
        #pragma unroll
        for (int i = 0; i < KTOP; ++i) {
            bool in = (fabsf(c4[i].x - mean[0]) <= sd[0]) &&
                      (fabsf(c4[i].y - mean[1]) <= sd[1]) &&
                      (fabsf(c4[i].z - mean[2]) <= sd[2]);
            if (in) { wsum += 1.f; acc[0] += c4[i].x; acc[1] += c4[i].y; acc[2] += c4[i].z; }
        }
        float inv = 1.f / (wsum + 1e-6f);
        #pragma unroll
        for (int c = 0; c < 3; ++c) {
            float v = acc[c] * inv;
            voted[t][c] = v;
            out[NB * 9 + NB * 3 + ((size_t)b * NKP + t) * 3 + c] = v;
        }
    }
    __syncthreads();

    if (t == 0) {
        float A[NKP][3], Bv[NKP][3];
        float cA[3] = {0, 0, 0}, cB[3] = {0, 0, 0};
        for (int nn = 0; nn < NKP; ++nn) {
            for (int c = 0; c < 3; ++c) {
                A[nn][c]  = meshS[nn * 3 + c];
                Bv[nn][c] = voted[nn][c];
                cA[c] += A[nn][c];
                cB[c] += Bv[nn][c];
            }
        }
        for (int c = 0; c < 3; ++c) { cA[c] *= (1.0f / NKP); cB[c] *= (1.0f / NKP); }
        float H[3][3] = {{0,0,0},{0,0,0},{0,0,0}};
        for (int nn = 0; nn < NKP; ++nn)
            for (int i = 0; i < 3; ++i)
                for (int j = 0; j < 3; ++j)
                    H[i][j] += (A[nn][i] - cA[i]) * (Bv[nn][j] - cB[j]);
        float Km[3][3];
        for (int i = 0; i < 3; ++i)
            for (int j = 0; j < 3; ++j) {
                float s = 0;
                for (int l = 0; l < 3; ++l) s += H[l][i] * H[l][j];
                Km[i][j] = s;
            }
        float V[3][3] = {{1,0,0},{0,1,0},{0,0,1}};
        for (int sweep = 0; sweep < 5; ++sweep) {
            for (int p = 0; p < 2; ++p) {
                for (int q = p + 1; q < 3; ++q) {
                    float apq = Km[p][q];
                    float app = Km[p][p], aqq = Km[q][q];
                    if (fabsf(apq) <= 1e-12f * (fabsf(app) + fabsf(aqq)) || apq == 0.0f) continue;
                    float theta = (aqq - app) * rcp_fast(2.0f * apq);
                    float tj = ((theta >= 0.0f) ? 1.0f : -1.0f) *
                               rcp_fast(fabsf(theta) + sqrt_fast(theta * theta + 1.0f));
                    float cj = rsq_fast(tj * tj + 1.0f);
                    float sj = tj * cj;
                    for (int l = 0; l < 3; ++l) {
                        float klp = Km[l][p], klq = Km[l][q];
                        Km[l][p] = cj * klp - sj * klq;
                        Km[l][q] = sj * klp + cj * klq;
                    }
                    for (int l = 0; l < 3; ++l) {
                        float kpl = Km[p][l], kql = Km[q][l];
                        Km[p][l] = cj * kpl - sj * kql;
                        Km[q][l] = sj * kpl + cj * kql;
                    }
                    for (int l = 0; l < 3; ++l) {
                        float vlp = V[l][p], vlq = V[l][q];
                        V[l][p] = cj * vlp - sj * vlq;
                        V[l][q] = sj * vlp + cj * vlq;
                    }
                }
            }
        }
        float eig[3] = {Km[0][0], Km[1][1], Km[2][2]};
        int ord[3] = {0, 1, 2};
        if (eig[ord[0]] < eig[ord[1]]) { int tmp = ord[0]; ord[0] = ord[1]; ord[1] = tmp; }
        if (eig[ord[1]] < eig[ord[2]]) { int tmp = ord[1]; ord[1] = ord[2]; ord[2] = tmp; }
        if (eig[ord[0]] < eig[ord[1]]) { int tmp = ord[0]; ord[0] = ord[1]; ord[1] = tmp; }
        float detH =
            H[0][0] * (H[1][1] * H[2][2] - H[1][2] * H[2][1]) -
            H[0][1] * (H[1][0] * H[2][2] - H[1][2] * H[2][0]) +
            H[0][2] * (H[1][0] * H[2][1] - H[1][1] * H[2][0]);
        float dsign[3] = {1.0f, 1.0f, (detH < 0.0f) ? -1.0f : 1.0f};
        float R[3][3] = {{0,0,0},{0,0,0},{0,0,0}};
        for (int k = 0; k < 3; ++k) {
            int c = ord[k];
            float s = sqrt_fast(fmaxf(eig[c], 0.0f));
            float invs = rcp_fast(fmaxf(s, 1e-12f));
            float u[3];
            for (int l = 0; l < 3; ++l) {
                float a2 = 0;
                for (int mm = 0; mm < 3; ++mm) a2 += H[l][mm] * V[mm][c];
                u[l] = a2 * invs;
            }
            for (int r = 0; r < 3; ++r)
                for (int cc = 0; cc < 3; ++cc)
                    R[r][cc] += dsign[k] * V[r][c] * u[cc];
        }
        float tv[3];
        for (int c = 0; c < 3; ++c) {
            float a2 = 0;
            for (int mm = 0; mm < 3; ++mm) a2 += R[c][mm] * cA[mm];
            tv[c] = cB[c] - a2;
        }
        for (int r = 0; r < 3; ++r)
            for (int c = 0; c < 3; ++c)
                out[(size_t)b * 9 + r * 3 + c] = R[r][c];
        for (int c = 0; c < 3; ++c)
            out[NB * 9 + (size_t)b * 3 + c] = tv[c];
    }
}

extern "C" void kernel_launch(void* const* d_in, const int* in_sizes, int n_in,
                              void* d_out, int out_size, void* d_ws, size_t ws_size,
                              hipStream_t stream) {
    const float* pcld = (const float*)d_in[0];   // [64,12288,3]
    const float* kpts = (const float*)d_in[1];   // [64,12288,8,3]
    const float* cpt  = (const float*)d_in[2];   // [64,12288,1,3]
    const float* seg  = (const float*)d_in[3];   // [64,12288,1]
    const float* mesh = (const float*)d_in[4];   // [64,9,3]
    float* out = (float*)d_out;                  // 576 (R) + 192 (t) + 1728 (voted)

    const size_t need = (size_t)NB * WS_STRIDE * sizeof(u64);   // 160 KB
    if (d_ws != nullptr && ws_size >= need) {
        u64* ws = (u64*)d_ws;
        pose_filter<<<NB * CHUNKS, TPB_A, 0, stream>>>(seg, ws);
        pose_solve<<<NB, TPB_B, 0, stream>>>(pcld, kpts, cpt, seg, mesh, ws, out);
    } else {
        pose_fused<<<NB, T, 0, stream>>>(pcld, kpts, cpt, seg, mesh, out);
    }
}